// Round 9
// baseline (370.302 us; speedup 1.0000x reference)
//
#include <hip/hip_runtime.h>
#include <hip/hip_bf16.h>
#include <stdint.h>

// ---------------------------------------------------------------------------
// RG-LRU block: T=8192, D_MODEL=768, D_RNN=1024, KW=4.
// Round 15: BN=256 dense GEMM -> T3+T4 counted-vmcnt pipeline, depth-2:
//  - BK=32, triple-buffered LDS (72 KB) -> still 2 blocks/CU (grid-capped).
//  - per k-iter: stage tile it+2 (3 uniform global_load_lds/thread) ->
//    s_waitcnt vmcnt(6) (9 in flight, oldest tile done; NEVER 0 in loop) ->
//    s_barrier -> 16 MFMA/wave -> s_barrier.  24/32 iters (K=768/1024).
//  - old loop exposed full ~900cy HBM latency per iter (issue 6 loads then
//    drain vmcnt(0)); counters: MfmaUtil 12%, VALUBusy 17% -> 70% wait.
//  - load counts uniform by construction (1 A + 2 B per thread) — no tails.
// conv (r6 body, closed ~68), out-GEMM (BN=64 old loop), prep, scans (r14
// vectorized) unchanged.
// ---------------------------------------------------------------------------

#define T_LEN 8192
#define DM 768
#define DR 1024
#define NC 512   // scan chunks
#define CL 16    // chunk length

typedef __bf16 bf16x8 __attribute__((ext_vector_type(8)));
typedef float  f32x4  __attribute__((ext_vector_type(4)));

#define AS1 __attribute__((address_space(1)))
#define AS3 __attribute__((address_space(3)))

__device__ __forceinline__ void cp16_g2l(const void* g, void* l) {
    __builtin_amdgcn_global_load_lds((const AS1 void*)g, (AS3 void*)l, 16, 0, 0);
}

__device__ __forceinline__ float gelu_tanh(float x) {
    const float inner = 0.7978845608028654f * (x + 0.044715f * x * x * x);
    return 0.5f * x * (1.f + tanhf(inner));
}

// exact bf16 -> f32
__device__ __forceinline__ float b2f(unsigned short u) {
    union { unsigned int i; float f; } cv;
    cv.i = ((unsigned int)u) << 16;
    return cv.f;
}

// ---------------------------------------------------------------------------
// Dense GEMM: C[m,n] = sum_k A[m,k]*B[n,k] (+bias[n]).  BM=128.
// Grid: (M/128, N/BN) — m fastest (id%8 = m%8: all n-blocks of an m-tile
// share one XCD -> A-slice L2-resident).
// BN=256: 512 thr, 8 waves (2m x 4n), 64x64/wave. BK=32 triple-buffered
//   counted-vmcnt pipeline (see header). 32-wide rows = 4 chunks; LDS slot s
//   at row r holds chunk s ^ ((r>>1)&3) (conv-style, bank-clean).
// BN=64:  256 thr, 4 waves (2m x 2n), BK=64 classic 2-barrier loop.
// EPI: 0 = fp32 +bias; 1 = bf16 +bias; 2 = split (gelu->Cv / shift->D2).
// ---------------------------------------------------------------------------
template<int BN, int EPI>
__global__ __launch_bounds__((BN == 256) ? 512 : 256, (BN == 256) ? 4 : 2)
void gemm_mfma(const __hip_bfloat16* __restrict__ A,
               const __hip_bfloat16* __restrict__ B,
               const float* __restrict__ bias,
               void* __restrict__ Cv,
               int K, int lda, int N,
               __hip_bfloat16* __restrict__ D2)
{
    const int tid  = threadIdx.x;
    const int lane = tid & 63;
    const int wave = tid >> 6;
    const size_t m0 = (size_t)blockIdx.x * 128;   // XCD = blockIdx.x % 8
    const int    n0 = blockIdx.y * BN;
    const int frow = lane & 15;
    const int fq   = lane >> 4;

    if constexpr (BN == 256) {
        // ---- counted-vmcnt pipeline, BK=32, depth-2 prefetch ----
        __shared__ __bf16 As[3][128 * 32];   // 3 x 8 KB
        __shared__ __bf16 Bs[3][256 * 32];   // 3 x 16 KB  (total 72 KB)

        const int wm = (wave >> 2) * 64;     // 2 m-halves
        const int wn = (wave & 3) * 64;      // 4 n-quarters

        f32x4 acc[4][4];
#pragma unroll
        for (int i = 0; i < 4; ++i)
#pragma unroll
            for (int j = 0; j < 4; ++j)
                acc[i][j] = f32x4{0.f, 0.f, 0.f, 0.f};

        auto stage = [&](int buf, int kc) {
            {   // A: 128 rows x 4 chunks = 512 chunks, 1/thread
                const int lin = tid;
                const int rr  = lin >> 2;
                const int gc  = (lin & 3) ^ ((rr >> 1) & 3);
                cp16_g2l(A + (m0 + rr) * (size_t)lda + kc + gc * 8, &As[buf][lin * 8]);
            }
            // B: 256 rows x 4 chunks = 1024 chunks, 2/thread
#pragma unroll
            for (int q = 0; q < 2; ++q) {
                const int lin = q * 512 + tid;
                const int rr  = lin >> 2;
                const int gc  = (lin & 3) ^ ((rr >> 1) & 3);
                cp16_g2l(B + (size_t)(n0 + rr) * K + kc + gc * 8, &Bs[buf][lin * 8]);
            }
        };

        const int NK = K >> 5;               // 24 (K=768) / 32 (K=1024)
        stage(0, 0);                         // 3 loads/wave in flight
        stage(1, 32);                        // 6

        for (int it = 0; it < NK; ++it) {
            const int cur = it % 3;
            if (it + 2 < NK) {
                stage((it + 2) % 3, (it + 2) * 32);               // 9 in flight
                asm volatile("s_waitcnt vmcnt(6)" ::: "memory");  // tile it done
            } else if (it + 1 < NK) {
                asm volatile("s_waitcnt vmcnt(3)" ::: "memory");
            } else {
                asm volatile("s_waitcnt vmcnt(0)" ::: "memory");
            }
            __builtin_amdgcn_s_barrier();        // tile it visible to all waves
            __builtin_amdgcn_sched_barrier(0);

            const __bf16* Ar = &As[cur][0];
            const __bf16* Br = &Bs[cur][0];
            bf16x8 af[4], bfr[4];
#pragma unroll
            for (int mi = 0; mi < 4; ++mi) {
                const int R = wm + mi * 16 + frow;
                af[mi] = *(const bf16x8*)&Ar[R * 32 + ((fq ^ ((R >> 1) & 3)) * 8)];
            }
#pragma unroll
            for (int ni = 0; ni < 4; ++ni) {
                const int R = wn + ni * 16 + frow;
                bfr[ni] = *(const bf16x8*)&Br[R * 32 + ((fq ^ ((R >> 1) & 3)) * 8)];
            }
#pragma unroll
            for (int mi = 0; mi < 4; ++mi)
#pragma unroll
                for (int ni = 0; ni < 4; ++ni)
                    acc[mi][ni] = __builtin_amdgcn_mfma_f32_16x16x32_bf16(
                        af[mi], bfr[ni], acc[mi][ni], 0, 0, 0);

            __builtin_amdgcn_sched_barrier(0);
            __builtin_amdgcn_s_barrier();        // buf cur reads done before overwrite
            __builtin_amdgcn_sched_barrier(0);
        }

        const int er = fq * 4;
        const int ec = frow;
#pragma unroll
        for (int ni = 0; ni < 4; ++ni) {
            const int n = n0 + wn + ni * 16 + ec;
            const float bv = bias ? bias[n] : 0.f;
#pragma unroll
            for (int mi = 0; mi < 4; ++mi) {
#pragma unroll
                for (int r2 = 0; r2 < 4; ++r2) {
                    const size_t m = m0 + wm + mi * 16 + er + r2;
                    const float v = acc[mi][ni][r2] + bv;
                    if (EPI == 0) {
                        ((float*)Cv)[m * (size_t)N + n] = v;
                    } else if (EPI == 1) {
                        ((__hip_bfloat16*)Cv)[m * (size_t)N + n] = __float2bfloat16(v);
                    } else {
                        if (n < 1024)
                            ((__hip_bfloat16*)Cv)[m * 1024 + n] = __float2bfloat16(gelu_tanh(v));
                        else
                            D2[(m + 3) * 1024 + (n - 1024)] = __float2bfloat16(v);
                    }
                }
            }
        }
    } else {
        // ---- classic 2-barrier BK=64 loop (out-GEMM) ----
        constexpr int NI = 2;                // BN=64, 2 n-waves
        __shared__ __bf16 As[128 * 64];
        __shared__ __bf16 Bs[BN * 64];

        const int wm = (wave >> 1) * 64;
        const int wn = (wave & 1) * (BN / 2);

        f32x4 acc[4][NI];
#pragma unroll
        for (int i = 0; i < 4; ++i)
#pragma unroll
            for (int j = 0; j < NI; ++j)
                acc[i][j] = f32x4{0.f, 0.f, 0.f, 0.f};

        for (int k0 = 0; k0 < K; k0 += 64) {
            __syncthreads();
#pragma unroll
            for (int q = 0; q < 4; ++q) {
                const int lin = q * 256 + tid;
                const int rr  = lin >> 3;
                const int gc  = (lin & 7) ^ (rr & 7);
                cp16_g2l(A + (m0 + rr) * (size_t)lda + k0 + gc * 8, &As[lin * 8]);
            }
#pragma unroll
            for (int q = 0; q < BN * 8 / 256; ++q) {
                const int lin = q * 256 + tid;
                const int rr  = lin >> 3;
                const int gc  = (lin & 7) ^ (rr & 7);
                cp16_g2l(B + (size_t)(n0 + rr) * K + k0 + gc * 8, &Bs[lin * 8]);
            }
            __syncthreads();

#pragma unroll
            for (int ks = 0; ks < 2; ++ks) {
                bf16x8 af[4], bfr[NI];
#pragma unroll
                for (int mi = 0; mi < 4; ++mi) {
                    const int R = wm + mi * 16 + frow;
                    af[mi] = *(const bf16x8*)&As[R * 64 + (((ks * 4 + fq) ^ (R & 7)) * 8)];
                }
#pragma unroll
                for (int ni = 0; ni < NI; ++ni) {
                    const int R = wn + ni * 16 + frow;
                    bfr[ni] = *(const bf16x8*)&Bs[R * 64 + (((ks * 4 + fq) ^ (R & 7)) * 8)];
                }
#pragma unroll
                for (int mi = 0; mi < 4; ++mi)
#pragma unroll
                    for (int ni = 0; ni < NI; ++ni)
                        acc[mi][ni] = __builtin_amdgcn_mfma_f32_16x16x32_bf16(
                            af[mi], bfr[ni], acc[mi][ni], 0, 0, 0);
            }
        }

        const int er = fq * 4;
        const int ec = frow;
#pragma unroll
        for (int ni = 0; ni < NI; ++ni) {
            const int n = n0 + wn + ni * 16 + ec;
            const float bv = bias ? bias[n] : 0.f;
#pragma unroll
            for (int mi = 0; mi < 4; ++mi) {
#pragma unroll
                for (int r2 = 0; r2 < 4; ++r2) {
                    const size_t m = m0 + wm + mi * 16 + er + r2;
                    const float v = acc[mi][ni][r2] + bv;
                    if (EPI == 0) {
                        ((float*)Cv)[m * (size_t)N + n] = v;
                    } else if (EPI == 1) {
                        ((__hip_bfloat16*)Cv)[m * (size_t)N + n] = __float2bfloat16(v);
                    } else {
                        if (n < 1024)
                            ((__hip_bfloat16*)Cv)[m * 1024 + n] = __float2bfloat16(gelu_tanh(v));
                        else
                            D2[(m + 3) * 1024 + (n - 1024)] = __float2bfloat16(v);
                    }
                }
            }
        }
    }
}

// ---------------------------------------------------------------------------
// Conv GEMM with shift reuse: bc[t,o] = sum_s sum_i W[o][s*1024+i]*bbp[t+s][i].
// Per 32-col k-tile: stage A halo (132 rows x 32 cols) ONCE + 4 B shift tiles
// (128 x 32 each), then 4 shifts x 16 MFMA per wave per barrier.  32 k-iters.
// 32-wide rows = 4 chunks; slot s at row r holds chunk s ^ ((r>>1)&3).
// (r6 body — pipeline variants r7/r11 both regressed: cross-block overlap at
// 2 blocks/CU beats 1-block/CU double-buffering here. Conv closed ~68 us.)
// ---------------------------------------------------------------------------
__global__ __launch_bounds__(256)
void conv_mfma(const __hip_bfloat16* __restrict__ bbp,
               const __hip_bfloat16* __restrict__ W,
               __hip_bfloat16* __restrict__ C)
{
    __shared__ __bf16 As[132 * 32];        // 8.25 KB halo tile
    __shared__ __bf16 Bs[4 * 128 * 32];    // 32 KB, 4 shift tiles

    const int tid  = threadIdx.x;
    const int lane = tid & 63;
    const int wave = tid >> 6;
    const size_t m0 = (size_t)blockIdx.x * 128;   // XCD = blockIdx.x % 8
    const int    n0 = blockIdx.y * 128;
    const int wm = (wave >> 1) * 64;
    const int wn = (wave & 1) * 64;

    f32x4 acc[4][4];
#pragma unroll
    for (int i = 0; i < 4; ++i)
#pragma unroll
        for (int j = 0; j < 4; ++j)
            acc[i][j] = f32x4{0.f, 0.f, 0.f, 0.f};

    const int frow = lane & 15;
    const int fq   = lane >> 4;

    for (int kc = 0; kc < 1024; kc += 32) {
        __syncthreads();
        // A halo: 132 rows x 4 chunks = 528 chunks (512 + 16 masked)
#pragma unroll
        for (int q = 0; q < 2; ++q) {
            const int lin = q * 256 + tid;
            const int rr  = lin >> 2;
            const int gc  = (lin & 3) ^ ((rr >> 1) & 3);
            cp16_g2l(bbp + (m0 + rr) * 1024 + kc + gc * 8, &As[lin * 8]);
        }
        if (tid < 16) {
            const int lin = 512 + tid;
            const int rr  = lin >> 2;
            const int gc  = (lin & 3) ^ ((rr >> 1) & 3);
            cp16_g2l(bbp + (m0 + rr) * 1024 + kc + gc * 8, &As[lin * 8]);
        }
        // B: 4 shift tiles, each 128 rows x 4 chunks = 512 chunks
#pragma unroll
        for (int s = 0; s < 4; ++s)
#pragma unroll
            for (int q = 0; q < 2; ++q) {
                const int lin = q * 256 + tid;
                const int rr  = lin >> 2;
                const int gc  = (lin & 3) ^ ((rr >> 1) & 3);
                cp16_g2l(W + (size_t)(n0 + rr) * 4096 + s * 1024 + kc + gc * 8,
                         &Bs[s * 4096 + lin * 8]);
            }
        __syncthreads();

#pragma unroll
        for (int s = 0; s < 4; ++s) {
            bf16x8 af[4], bfr[4];
#pragma unroll
            for (int mi = 0; mi < 4; ++mi) {
                const int R = wm + mi * 16 + frow + s;       // shifted row
                af[mi] = *(const bf16x8*)&As[R * 32 + ((fq ^ ((R >> 1) & 3)) * 8)];
            }
#pragma unroll
            for (int ni = 0; ni < 4; ++ni) {
                const int R = wn + ni * 16 + frow;
                bfr[ni] = *(const bf16x8*)&Bs[s * 4096 + R * 32 + ((fq ^ ((R >> 1) & 3)) * 8)];
            }
#pragma unroll
            for (int mi = 0; mi < 4; ++mi)
#pragma unroll
                for (int ni = 0; ni < 4; ++ni)
                    acc[mi][ni] = __builtin_amdgcn_mfma_f32_16x16x32_bf16(
                        af[mi], bfr[ni], acc[mi][ni], 0, 0, 0);
        }
    }

    const int er = fq * 4;
    const int ec = frow;
#pragma unroll
    for (int ni = 0; ni < 4; ++ni) {
        const int n = n0 + wn + ni * 16 + ec;
#pragma unroll
        for (int mi = 0; mi < 4; ++mi)
#pragma unroll
            for (int r2 = 0; r2 < 4; ++r2) {
                const size_t m = m0 + wm + mi * 16 + er + r2;
                C[m * 1024 + n] = __float2bfloat16(acc[mi][ni][r2]);
            }
    }
}

// ---------------------------------------------------------------------------
// Vectorized prep: 4 elems/thread for f32->bf16 conversions (float4 load,
// ushort4 store); conv repack 1 thread per (o,i): float4 read of 4 taps,
// 4 coalesced k-plane stores; bbp pad rows zeroed.
// ---------------------------------------------------------------------------
#define G_X   1572864                 // 8192*768/4
#define G_W1  (G_X + 393216)          // + 2048*768/4
#define G_WRG (G_W1 + 524288)         // + 2048*1024/4
#define G_WO  (G_WRG + 196608)        // + 768*1024/4
#define G_CW  (G_WO + 1048576)        // + 1024*1024 (o,i) pairs
#define G_PAD (G_CW + 768)            // + 3072/4 pad groups
#define PREP_BLOCKS (G_PAD / 256)     // 14595

__device__ __forceinline__ unsigned short bfu(float f) {
    __hip_bfloat16 h = __float2bfloat16(f);
    union { __hip_bfloat16 h; unsigned short u; } cv; cv.h = h; return cv.u;
}
__device__ __forceinline__ void cvt4(const float* __restrict__ s,
                                     __hip_bfloat16* __restrict__ d) {
    const float4 v = *(const float4*)s;
    ushort4 o; o.x = bfu(v.x); o.y = bfu(v.y); o.z = bfu(v.z); o.w = bfu(v.w);
    *(ushort4*)d = o;
}

__global__ void prep_kernel(const float* __restrict__ x, const float* __restrict__ w1,
                            const float* __restrict__ w_rg, const float* __restrict__ w_out,
                            const float* __restrict__ conv_w,
                            __hip_bfloat16* __restrict__ xb, __hip_bfloat16* __restrict__ w1b,
                            __hip_bfloat16* __restrict__ w_rgb, __hip_bfloat16* __restrict__ w_outb,
                            __hip_bfloat16* __restrict__ wbigb, __hip_bfloat16* __restrict__ bbp)
{
    const int g = blockIdx.x * 256 + threadIdx.x;
    if (g < G_X) {
        const size_t i = 4 * (size_t)g;            cvt4(x + i, xb + i);
    } else if (g < G_W1) {
        const size_t i = 4 * (size_t)(g - G_X);    cvt4(w1 + i, w1b + i);
    } else if (g < G_WRG) {
        const size_t i = 4 * (size_t)(g - G_W1);   cvt4(w_rg + i, w_rgb + i);
    } else if (g < G_WO) {
        const size_t i = 4 * (size_t)(g - G_WRG);  cvt4(w_out + i, w_outb + i);
    } else if (g < G_CW) {
        const int n = g - G_WO;                    // n = o*1024 + i
        const int o = n >> 10, i = n & 1023;
        const float4 v = *(const float4*)(conv_w + (size_t)n * 4); // 4 taps, contiguous
        __hip_bfloat16* base = wbigb + (size_t)o * 4096 + i;
        base[0]    = __float2bfloat16(v.x);        // k=0 plane (coalesced per k)
        base[1024] = __float2bfloat16(v.y);
        base[2048] = __float2bfloat16(v.z);
        base[3072] = __float2bfloat16(v.w);
    } else if (g < G_PAD) {
        const int i = (g - G_CW) * 4;
        ushort4 z; z.x = 0; z.y = 0; z.z = 0; z.w = 0;
        *(ushort4*)(bbp + i) = z;                  // rows 0..2 zero
    }
}

// ---------------------------------------------------------------------------
// Scans, vectorized: thread owns 4 consecutive channels (c0 = tid*4);
// ushort4 (8B/lane) bf16 loads, float4 carries, ushort4 z stores.
// Grid = NC blocks (512 = 2/CU), 256 threads cover all 1024 channels.
// ---------------------------------------------------------------------------
__global__ void scan_pass1(const __hip_bfloat16* __restrict__ gp,
                           const __hip_bfloat16* __restrict__ bc,
                           const float* __restrict__ Lambda,
                           float* __restrict__ ch, float* __restrict__ ca)
{
    const int c0 = threadIdx.x * 4;
    const int j  = blockIdx.x;
    const float4 Lv = *(const float4*)(Lambda + c0);
    float cl[4] = { -8.f * log1pf(expf(Lv.x)), -8.f * log1pf(expf(Lv.y)),
                    -8.f * log1pf(expf(Lv.z)), -8.f * log1pf(expf(Lv.w)) };
    float h[4]  = {0.f, 0.f, 0.f, 0.f};
    float ap[4] = {1.f, 1.f, 1.f, 1.f};
    const int t0 = j * CL;
    for (int tt = 0; tt < CL; ++tt) {
        const long t = t0 + tt;
        const ushort4 igu = *(const ushort4*)(gp + t * 2048 + c0);
        const ushort4 rgu = *(const ushort4*)(gp + t * 2048 + 1024 + c0);
        const ushort4 bcu = *(const ushort4*)(bc + t * 1024 + c0);
        const unsigned short igs[4] = {igu.x, igu.y, igu.z, igu.w};
        const unsigned short rgs[4] = {rgu.x, rgu.y, rgu.z, rgu.w};
        const unsigned short bcs[4] = {bcu.x, bcu.y, bcu.z, bcu.w};
#pragma unroll
        for (int k = 0; k < 4; ++k) {
            const float ig = 1.f / (1.f + expf(-b2f(igs[k])));
            const float rg = 1.f / (1.f + expf(-b2f(rgs[k])));
            const float a  = expf(cl[k] * rg);
            const float gx = sqrtf(fmaxf(0.f, 1.f - a * a)) * ig * b2f(bcs[k]);
            h[k]  = fmaf(a, h[k], gx);
            ap[k] *= a;
        }
    }
    *(float4*)(ch + j * 1024 + c0) = make_float4(h[0], h[1], h[2], h[3]);
    *(float4*)(ca + j * 1024 + c0) = make_float4(ap[0], ap[1], ap[2], ap[3]);
}

__global__ void scan_combine(float* __restrict__ ch, const float* __restrict__ ca)
{
    const int c = blockIdx.x * 256 + threadIdx.x;
    float carry = 0.f;
    for (int j = 0; j < NC; ++j) {
        const float hj = ch[j * 1024 + c];
        const float aj = ca[j * 1024 + c];
        ch[j * 1024 + c] = carry;
        carry = fmaf(aj, carry, hj);
    }
}

// Rescan with carry; z = ab * y -> bf16 (zb aliases bc: same-element RMW per thread).
__global__ void scan_pass2(const __hip_bfloat16* __restrict__ gp, const __hip_bfloat16* bc,
                           const float* __restrict__ Lambda,
                           const float* __restrict__ carry_in,
                           const __hip_bfloat16* __restrict__ ab,
                           __hip_bfloat16* zb)
{
    const int c0 = threadIdx.x * 4;
    const int j  = blockIdx.x;
    const float4 Lv = *(const float4*)(Lambda + c0);
    float cl[4] = { -8.f * log1pf(expf(Lv.x)), -8.f * log1pf(expf(Lv.y)),
                    -8.f * log1pf(expf(Lv.z)), -8.f * log1pf(expf(Lv.w)) };
    const float4 cv = *(const float4*)(carry_in + j * 1024 + c0);
    float h[4] = {cv.x, cv.y, cv.z, cv.w};
    const int t0 = j * CL;
    for (int tt = 0; tt < CL; ++tt) {
        const long t = t0 + tt;
        const ushort4 igu = *(const ushort4*)(gp + t * 2048 + c0);
        const ushort4 rgu = *(const ushort4*)(gp + t * 2048 + 1024 + c0);
        const ushort4 bcu = *(const ushort4*)(bc + t * 1024 + c0);
        const ushort4 abu = *(const ushort4*)(ab + t * 1024 + c0);
        const unsigned short igs[4] = {igu.x, igu.y, igu.z, igu.w};
        const unsigned short rgs[4] = {rgu.x, rgu.y, rgu.z, rgu.w};
        const unsigned short bcs[4] = {bcu.x, bcu.y, bcu.z, bcu.w};
        const unsigned short abs_[4] = {abu.x, abu.y, abu.z, abu.w};
        ushort4 zo;
        unsigned short zs[4];
#pragma unroll
        for (int k = 0; k < 4; ++k) {
            const float ig = 1.f / (1.f + expf(-b2f(igs[k])));
            const float rg = 1.f / (1.f + expf(-b2f(rgs[k])));
            const float a  = expf(cl[k] * rg);
            const float gx = sqrtf(fmaxf(0.f, 1.f - a * a)) * ig * b2f(bcs[k]);
            h[k] = fmaf(a, h[k], gx);
            zs[k] = bfu(b2f(abs_[k]) * h[k]);
        }
        zo.x = zs[0]; zo.y = zs[1]; zo.z = zs[2]; zo.w = zs[3];
        *(ushort4*)(zb + t * 1024 + c0) = zo;
    }
}

extern "C" void kernel_launch(void* const* d_in, const int* in_sizes, int n_in,
                              void* d_out, int out_size, void* d_ws, size_t ws_size,
                              hipStream_t stream)
{
    const float* x      = (const float*)d_in[0];
    const float* w1     = (const float*)d_in[1];
    const float* b1     = (const float*)d_in[2];
    const float* conv_w = (const float*)d_in[3];
    const float* w_rg   = (const float*)d_in[4];
    const float* b_rg   = (const float*)d_in[5];
    const float* w_out  = (const float*)d_in[6];
    const float* b_out  = (const float*)d_in[7];
    const float* Lambda = (const float*)d_in[8];
    float* out = (float*)d_out;
    (void)in_sizes; (void)n_in; (void)out_size; (void)ws_size;

    // ---- workspace layout (~113 MB) ----
    char* p = (char*)d_ws;
    auto alloc = [&](size_t bytes) { char* r = p; p += (bytes + 255) & ~255ULL; return r; };
    __hip_bfloat16* gpre  = (__hip_bfloat16*)alloc(8192ULL * 2048 * 2); // 32 MB
    __hip_bfloat16* ab    = (__hip_bfloat16*)alloc(8192ULL * 1024 * 2); // 16 MB
    __hip_bfloat16* bbp   = (__hip_bfloat16*)alloc(8224ULL * 1024 * 2); // 16.8 MB
    __hip_bfloat16* bcb   = (__hip_bfloat16*)alloc(8192ULL * 1024 * 2); // 16 MB (later zb)
    __hip_bfloat16* wbigb = (__hip_bfloat16*)alloc(1024ULL * 4096 * 2); // 8 MB
    __hip_bfloat16* xb    = (__hip_bfloat16*)alloc(8192ULL * 768 * 2);  // 12 MB
    __hip_bfloat16* w1b   = (__hip_bfloat16*)alloc(2048ULL * 768 * 2);  // 3 MB
    __hip_bfloat16* w_rgb = (__hip_bfloat16*)alloc(2048ULL * 1024 * 2); // 4 MB
    __hip_bfloat16* w_outb= (__hip_bfloat16*)alloc(768ULL * 1024 * 2);  // 1.5 MB
    float*          chv   = (float*)alloc(NC * 1024ULL * 4);            // 2 MB
    float*          cav   = (float*)alloc(NC * 1024ULL * 4);            // 2 MB
    __hip_bfloat16* zb    = bcb;   // overlay

    prep_kernel<<<PREP_BLOCKS, 256, 0, stream>>>(x, w1, w_rg, w_out, conv_w,
                                                 xb, w1b, w_rgb, w_outb, wbigb, bbp);

    // h = x @ w1.T + b1, fused split: ab = bf16(gelu), bbp = bf16 (rows +3)
    {
        dim3 grid(T_LEN / 128, 2048 / 256);
        gemm_mfma<256, 2><<<grid, 512, 0, stream>>>(xb, w1b, b1, ab, DM, DM, 2048, bbp);
    }

    // bc = causal conv (shift-reuse kernel) -> bf16
    {
        dim3 grid(T_LEN / 128, 1024 / 128);
        conv_mfma<<<grid, 256, 0, stream>>>(bbp, wbigb, bcb);
    }

    // g_pre = bc @ w_rg.T + b_rg -> bf16
    {
        dim3 grid(T_LEN / 128, 2048 / 256);
        gemm_mfma<256, 1><<<grid, 512, 0, stream>>>(bcb, w_rgb, b_rg, gpre, DR, DR, 2048, nullptr);
    }

    // chunked scan with fused gates; z = ab*y -> bf16 (overlays bcb)
    {
        scan_pass1<<<NC, 256, 0, stream>>>(gpre, bcb, Lambda, chv, cav);
        scan_combine<<<DR / 256, 256, 0, stream>>>(chv, cav);
        scan_pass2<<<NC, 256, 0, stream>>>(gpre, bcb, Lambda, chv, ab, zb);
    }

    // out = z @ w_out.T + b_out -> fp32
    {
        dim3 grid(T_LEN / 128, DM / 64);
        gemm_mfma<64, 0><<<grid, 256, 0, stream>>>(zb, w_outb, b_out, out, DR, DR, DM, nullptr);
    }
}

// Round 10
// 338.747 us; speedup vs baseline: 1.0932x; 1.0932x over previous
//
#include <hip/hip_runtime.h>
#include <hip/hip_bf16.h>
#include <stdint.h>

// ---------------------------------------------------------------------------
// RG-LRU block: T=8192, D_MODEL=768, D_RNN=1024, KW=4.
// Round 16: full revert to the r13 configuration (345.7 us measured best).
//  - r14 (vectorized scans, NC=512) = 355.5 and r15 (counted-vmcnt BN=256
//    gemm) = 370.3 both regressed; reverted.
//  - Third counted-vmcnt attempt lost to plain 2-barrier + wave-TLP: the
//    T3/T4 gains require the full 8-phase interleave (guide regime table),
//    not a barrier-pair loop with counted waits.
//  - Per-kernel rocprof durations proved unreliable across rounds (identical
//    gemm code: 84 us in r13's profile, <68 in r14/r15); trust totals only.
// Config: classic 512-thr BN=256 gemms (16 waves/CU), conv r6 body (closed
// ~68 us), vectorized prep, scalar scans NC=128/CL=64.
// ---------------------------------------------------------------------------

#define T_LEN 8192
#define DM 768
#define DR 1024
#define NC 128   // scan chunks
#define CL 64    // chunk length

typedef __bf16 bf16x8 __attribute__((ext_vector_type(8)));
typedef float  f32x4  __attribute__((ext_vector_type(4)));

#define AS1 __attribute__((address_space(1)))
#define AS3 __attribute__((address_space(3)))

__device__ __forceinline__ void cp16_g2l(const void* g, void* l) {
    __builtin_amdgcn_global_load_lds((const AS1 void*)g, (AS3 void*)l, 16, 0, 0);
}

__device__ __forceinline__ float gelu_tanh(float x) {
    const float inner = 0.7978845608028654f * (x + 0.044715f * x * x * x);
    return 0.5f * x * (1.f + tanhf(inner));
}

// ---------------------------------------------------------------------------
// Dense GEMM: C[m,n] = sum_k A[m,k]*B[n,k] (+bias[n]).  BM=128, BK=64.
// Grid: (M/128, N/BN) — m fastest (id%8 = m%8: all n-blocks of an m-tile
// share one XCD -> A-slice L2-resident).
// LDS rows are 64 elements = 8 16B chunks; chunk slot s at row r holds global
// chunk s ^ (r & 7)  -> every wave64 ds_read_b128 is perfectly bank-balanced.
// BN=256: 512 thr, 8 waves (2m x 4n), 64x64 per wave, NI=4, acc 64 VGPR ->
//         16 waves/CU (4/SIMD) — doubled TLP covers vmcnt(0) drains.
// BN=64:  256 thr, 4 waves (2m x 2n), 64x32 per wave, NI=2.
// EPI: 0 = fp32 +bias; 1 = bf16 +bias; 2 = split (gelu->Cv / shift->D2).
// ---------------------------------------------------------------------------
template<int BN, int EPI>
__global__ __launch_bounds__((BN == 256) ? 512 : 256, (BN == 256) ? 4 : 2)
void gemm_mfma(const __hip_bfloat16* __restrict__ A,
               const __hip_bfloat16* __restrict__ B,
               const float* __restrict__ bias,
               void* __restrict__ Cv,
               int K, int lda, int N,
               __hip_bfloat16* __restrict__ D2)
{
    constexpr int TH  = (BN == 256) ? 512 : 256;   // threads
    constexpr int NWN = (BN == 256) ? 4 : 2;       // n-waves
    constexpr int NI  = BN / (16 * NWN);           // n-frags per wave (4 or 2)
    __shared__ __bf16 As[128 * 64];
    __shared__ __bf16 Bs[BN * 64];

    const int tid  = threadIdx.x;
    const int lane = tid & 63;
    const int wave = tid >> 6;
    const size_t m0 = (size_t)blockIdx.x * 128;   // XCD = blockIdx.x % 8
    const int    n0 = blockIdx.y * BN;
    const int wm = (wave / NWN) * 64;
    const int wn = (wave % NWN) * (NI * 16);

    f32x4 acc[4][NI];
#pragma unroll
    for (int i = 0; i < 4; ++i)
#pragma unroll
        for (int j = 0; j < NI; ++j)
            acc[i][j] = f32x4{0.f, 0.f, 0.f, 0.f};

    const int frow = lane & 15;
    const int fq   = lane >> 4;

    for (int k0 = 0; k0 < K; k0 += 64) {
        __syncthreads();   // previous iteration's LDS reads complete
        // A tile: 128 rows x 8 chunks = 1024 chunks
#pragma unroll
        for (int q = 0; q < 1024 / TH; ++q) {
            const int lin = q * TH + tid;
            const int rr  = lin >> 3;
            const int gc  = (lin & 7) ^ (rr & 7);
            cp16_g2l(A + (m0 + rr) * (size_t)lda + k0 + gc * 8, &As[lin * 8]);
        }
        // B tile: BN rows x 8 chunks
#pragma unroll
        for (int q = 0; q < BN * 8 / TH; ++q) {
            const int lin = q * TH + tid;
            const int rr  = lin >> 3;
            const int gc  = (lin & 7) ^ (rr & 7);
            cp16_g2l(B + (size_t)(n0 + rr) * K + k0 + gc * 8, &Bs[lin * 8]);
        }
        __syncthreads();   // includes vmcnt(0) drain

#pragma unroll
        for (int ks = 0; ks < 2; ++ks) {
            bf16x8 af[4], bfr[NI];
#pragma unroll
            for (int mi = 0; mi < 4; ++mi) {
                const int R = wm + mi * 16 + frow;
                af[mi] = *(const bf16x8*)&As[R * 64 + (((ks * 4 + fq) ^ (R & 7)) * 8)];
            }
#pragma unroll
            for (int ni = 0; ni < NI; ++ni) {
                const int R = wn + ni * 16 + frow;
                bfr[ni] = *(const bf16x8*)&Bs[R * 64 + (((ks * 4 + fq) ^ (R & 7)) * 8)];
            }
#pragma unroll
            for (int mi = 0; mi < 4; ++mi)
#pragma unroll
                for (int ni = 0; ni < NI; ++ni)
                    acc[mi][ni] = __builtin_amdgcn_mfma_f32_16x16x32_bf16(
                        af[mi], bfr[ni], acc[mi][ni], 0, 0, 0);
        }
    }

    // C/D layout: col = lane&15, row = (lane>>4)*4 + reg
    const int er = fq * 4;
    const int ec = frow;
#pragma unroll
    for (int ni = 0; ni < NI; ++ni) {
        const int n = n0 + wn + ni * 16 + ec;
        const float bv = bias ? bias[n] : 0.f;
#pragma unroll
        for (int mi = 0; mi < 4; ++mi) {
#pragma unroll
            for (int r2 = 0; r2 < 4; ++r2) {
                const size_t m = m0 + wm + mi * 16 + er + r2;
                const float v = acc[mi][ni][r2] + bv;
                if (EPI == 0) {
                    ((float*)Cv)[m * (size_t)N + n] = v;
                } else if (EPI == 1) {
                    ((__hip_bfloat16*)Cv)[m * (size_t)N + n] = __float2bfloat16(v);
                } else {
                    if (n < 1024)
                        ((__hip_bfloat16*)Cv)[m * 1024 + n] = __float2bfloat16(gelu_tanh(v));
                    else
                        D2[(m + 3) * 1024 + (n - 1024)] = __float2bfloat16(v);
                }
            }
        }
    }
}

// ---------------------------------------------------------------------------
// Conv GEMM with shift reuse: bc[t,o] = sum_s sum_i W[o][s*1024+i]*bbp[t+s][i].
// Per 32-col k-tile: stage A halo (132 rows x 32 cols) ONCE + 4 B shift tiles
// (128 x 32 each), then 4 shifts x 16 MFMA per wave per barrier.  32 k-iters.
// 32-wide rows = 4 chunks; slot s at row r holds chunk s ^ ((r>>1)&3).
// (r6 body — pipeline variants r7/r11 both regressed: cross-block overlap at
// 2-3 blocks/CU beats 1-block/CU double-buffering here. Conv closed ~68 us.)
// ---------------------------------------------------------------------------
__global__ __launch_bounds__(256)
void conv_mfma(const __hip_bfloat16* __restrict__ bbp,
               const __hip_bfloat16* __restrict__ W,
               __hip_bfloat16* __restrict__ C)
{
    __shared__ __bf16 As[132 * 32];        // 8.25 KB halo tile
    __shared__ __bf16 Bs[4 * 128 * 32];    // 32 KB, 4 shift tiles

    const int tid  = threadIdx.x;
    const int lane = tid & 63;
    const int wave = tid >> 6;
    const size_t m0 = (size_t)blockIdx.x * 128;   // XCD = blockIdx.x % 8
    const int    n0 = blockIdx.y * 128;
    const int wm = (wave >> 1) * 64;
    const int wn = (wave & 1) * 64;

    f32x4 acc[4][4];
#pragma unroll
    for (int i = 0; i < 4; ++i)
#pragma unroll
        for (int j = 0; j < 4; ++j)
            acc[i][j] = f32x4{0.f, 0.f, 0.f, 0.f};

    const int frow = lane & 15;
    const int fq   = lane >> 4;

    for (int kc = 0; kc < 1024; kc += 32) {
        __syncthreads();
        // A halo: 132 rows x 4 chunks = 528 chunks (512 + 16 masked)
#pragma unroll
        for (int q = 0; q < 2; ++q) {
            const int lin = q * 256 + tid;
            const int rr  = lin >> 2;
            const int gc  = (lin & 3) ^ ((rr >> 1) & 3);
            cp16_g2l(bbp + (m0 + rr) * 1024 + kc + gc * 8, &As[lin * 8]);
        }
        if (tid < 16) {
            const int lin = 512 + tid;
            const int rr  = lin >> 2;
            const int gc  = (lin & 3) ^ ((rr >> 1) & 3);
            cp16_g2l(bbp + (m0 + rr) * 1024 + kc + gc * 8, &As[lin * 8]);
        }
        // B: 4 shift tiles, each 128 rows x 4 chunks = 512 chunks
#pragma unroll
        for (int s = 0; s < 4; ++s)
#pragma unroll
            for (int q = 0; q < 2; ++q) {
                const int lin = q * 256 + tid;
                const int rr  = lin >> 2;
                const int gc  = (lin & 3) ^ ((rr >> 1) & 3);
                cp16_g2l(W + (size_t)(n0 + rr) * 4096 + s * 1024 + kc + gc * 8,
                         &Bs[s * 4096 + lin * 8]);
            }
        __syncthreads();

#pragma unroll
        for (int s = 0; s < 4; ++s) {
            bf16x8 af[4], bfr[4];
#pragma unroll
            for (int mi = 0; mi < 4; ++mi) {
                const int R = wm + mi * 16 + frow + s;       // shifted row
                af[mi] = *(const bf16x8*)&As[R * 32 + ((fq ^ ((R >> 1) & 3)) * 8)];
            }
#pragma unroll
            for (int ni = 0; ni < 4; ++ni) {
                const int R = wn + ni * 16 + frow;
                bfr[ni] = *(const bf16x8*)&Bs[s * 4096 + R * 32 + ((fq ^ ((R >> 1) & 3)) * 8)];
            }
#pragma unroll
            for (int mi = 0; mi < 4; ++mi)
#pragma unroll
                for (int ni = 0; ni < 4; ++ni)
                    acc[mi][ni] = __builtin_amdgcn_mfma_f32_16x16x32_bf16(
                        af[mi], bfr[ni], acc[mi][ni], 0, 0, 0);
        }
    }

    const int er = fq * 4;
    const int ec = frow;
#pragma unroll
    for (int ni = 0; ni < 4; ++ni) {
        const int n = n0 + wn + ni * 16 + ec;
#pragma unroll
        for (int mi = 0; mi < 4; ++mi)
#pragma unroll
            for (int r2 = 0; r2 < 4; ++r2) {
                const size_t m = m0 + wm + mi * 16 + er + r2;
                C[m * 1024 + n] = __float2bfloat16(acc[mi][ni][r2]);
            }
    }
}

// ---------------------------------------------------------------------------
// Vectorized prep: 4 elems/thread for f32->bf16 conversions (float4 load,
// ushort4 store); conv repack 1 thread per (o,i): float4 read of 4 taps,
// 4 coalesced k-plane stores; bbp pad rows zeroed.
// ---------------------------------------------------------------------------
#define G_X   1572864                 // 8192*768/4
#define G_W1  (G_X + 393216)          // + 2048*768/4
#define G_WRG (G_W1 + 524288)         // + 2048*1024/4
#define G_WO  (G_WRG + 196608)        // + 768*1024/4
#define G_CW  (G_WO + 1048576)        // + 1024*1024 (o,i) pairs
#define G_PAD (G_CW + 768)            // + 3072/4 pad groups
#define PREP_BLOCKS (G_PAD / 256)     // 14595

__device__ __forceinline__ unsigned short bfu(float f) {
    __hip_bfloat16 h = __float2bfloat16(f);
    union { __hip_bfloat16 h; unsigned short u; } cv; cv.h = h; return cv.u;
}
__device__ __forceinline__ void cvt4(const float* __restrict__ s,
                                     __hip_bfloat16* __restrict__ d) {
    const float4 v = *(const float4*)s;
    ushort4 o; o.x = bfu(v.x); o.y = bfu(v.y); o.z = bfu(v.z); o.w = bfu(v.w);
    *(ushort4*)d = o;
}

__global__ void prep_kernel(const float* __restrict__ x, const float* __restrict__ w1,
                            const float* __restrict__ w_rg, const float* __restrict__ w_out,
                            const float* __restrict__ conv_w,
                            __hip_bfloat16* __restrict__ xb, __hip_bfloat16* __restrict__ w1b,
                            __hip_bfloat16* __restrict__ w_rgb, __hip_bfloat16* __restrict__ w_outb,
                            __hip_bfloat16* __restrict__ wbigb, __hip_bfloat16* __restrict__ bbp)
{
    const int g = blockIdx.x * 256 + threadIdx.x;
    if (g < G_X) {
        const size_t i = 4 * (size_t)g;            cvt4(x + i, xb + i);
    } else if (g < G_W1) {
        const size_t i = 4 * (size_t)(g - G_X);    cvt4(w1 + i, w1b + i);
    } else if (g < G_WRG) {
        const size_t i = 4 * (size_t)(g - G_W1);   cvt4(w_rg + i, w_rgb + i);
    } else if (g < G_WO) {
        const size_t i = 4 * (size_t)(g - G_WRG);  cvt4(w_out + i, w_outb + i);
    } else if (g < G_CW) {
        const int n = g - G_WO;                    // n = o*1024 + i
        const int o = n >> 10, i = n & 1023;
        const float4 v = *(const float4*)(conv_w + (size_t)n * 4); // 4 taps, contiguous
        __hip_bfloat16* base = wbigb + (size_t)o * 4096 + i;
        base[0]    = __float2bfloat16(v.x);        // k=0 plane (coalesced per k)
        base[1024] = __float2bfloat16(v.y);
        base[2048] = __float2bfloat16(v.z);
        base[3072] = __float2bfloat16(v.w);
    } else if (g < G_PAD) {
        const int i = (g - G_CW) * 4;
        ushort4 z; z.x = 0; z.y = 0; z.z = 0; z.w = 0;
        *(ushort4*)(bbp + i) = z;                  // rows 0..2 zero
    }
}

// Gates recomputed inline from g_pre (T x 2048 bf16) + bc (bf16):
__global__ void scan_pass1(const __hip_bfloat16* __restrict__ gp,
                           const __hip_bfloat16* __restrict__ bc,
                           const float* __restrict__ Lambda,
                           float* __restrict__ ch, float* __restrict__ ca)
{
    const int c = blockIdx.y * 256 + threadIdx.x;
    const int j = blockIdx.x;
    const float cl = -8.f * log1pf(expf(Lambda[c]));
    float h = 0.f, ap = 1.f;
    const int t0 = j * CL;
    for (int tt = 0; tt < CL; ++tt) {
        const int t = t0 + tt;
        const long gi = (long)t * 2048 + c;
        const float ig = 1.f / (1.f + expf(-__bfloat162float(gp[gi])));
        const float rg = 1.f / (1.f + expf(-__bfloat162float(gp[gi + 1024])));
        const float a  = expf(cl * rg);
        const float gx = sqrtf(fmaxf(0.f, 1.f - a * a)) * ig *
                         __bfloat162float(bc[(long)t * 1024 + c]);
        h  = fmaf(a, h, gx);
        ap *= a;
    }
    ch[j * 1024 + c] = h;
    ca[j * 1024 + c] = ap;
}

__global__ void scan_combine(float* __restrict__ ch, const float* __restrict__ ca)
{
    const int c = blockIdx.x * 256 + threadIdx.x;
    float carry = 0.f;
    for (int j = 0; j < NC; ++j) {
        const float hj = ch[j * 1024 + c];
        const float aj = ca[j * 1024 + c];
        ch[j * 1024 + c] = carry;
        carry = fmaf(aj, carry, hj);
    }
}

// Rescan with carry; z = ab * y -> bf16 (zb aliases bc: same-element RMW per thread).
__global__ void scan_pass2(const __hip_bfloat16* __restrict__ gp, const __hip_bfloat16* bc,
                           const float* __restrict__ Lambda,
                           const float* __restrict__ carry_in,
                           const __hip_bfloat16* __restrict__ ab,
                           __hip_bfloat16* zb)
{
    const int c = blockIdx.y * 256 + threadIdx.x;
    const int j = blockIdx.x;
    const float cl = -8.f * log1pf(expf(Lambda[c]));
    float h = carry_in[j * 1024 + c];
    const int t0 = j * CL;
    for (int tt = 0; tt < CL; ++tt) {
        const int t = t0 + tt;
        const long gi = (long)t * 2048 + c;
        const long bi = (long)t * 1024 + c;
        const float ig = 1.f / (1.f + expf(-__bfloat162float(gp[gi])));
        const float rg = 1.f / (1.f + expf(-__bfloat162float(gp[gi + 1024])));
        const float a  = expf(cl * rg);
        const float gx = sqrtf(fmaxf(0.f, 1.f - a * a)) * ig * __bfloat162float(bc[bi]);
        h = fmaf(a, h, gx);
        zb[bi] = __float2bfloat16(__bfloat162float(ab[bi]) * h);
    }
}

extern "C" void kernel_launch(void* const* d_in, const int* in_sizes, int n_in,
                              void* d_out, int out_size, void* d_ws, size_t ws_size,
                              hipStream_t stream)
{
    const float* x      = (const float*)d_in[0];
    const float* w1     = (const float*)d_in[1];
    const float* b1     = (const float*)d_in[2];
    const float* conv_w = (const float*)d_in[3];
    const float* w_rg   = (const float*)d_in[4];
    const float* b_rg   = (const float*)d_in[5];
    const float* w_out  = (const float*)d_in[6];
    const float* b_out  = (const float*)d_in[7];
    const float* Lambda = (const float*)d_in[8];
    float* out = (float*)d_out;
    (void)in_sizes; (void)n_in; (void)out_size; (void)ws_size;

    // ---- workspace layout (~113 MB) ----
    char* p = (char*)d_ws;
    auto alloc = [&](size_t bytes) { char* r = p; p += (bytes + 255) & ~255ULL; return r; };
    __hip_bfloat16* gpre  = (__hip_bfloat16*)alloc(8192ULL * 2048 * 2); // 32 MB
    __hip_bfloat16* ab    = (__hip_bfloat16*)alloc(8192ULL * 1024 * 2); // 16 MB
    __hip_bfloat16* bbp   = (__hip_bfloat16*)alloc(8224ULL * 1024 * 2); // 16.8 MB
    __hip_bfloat16* bcb   = (__hip_bfloat16*)alloc(8192ULL * 1024 * 2); // 16 MB (later zb)
    __hip_bfloat16* wbigb = (__hip_bfloat16*)alloc(1024ULL * 4096 * 2); // 8 MB
    __hip_bfloat16* xb    = (__hip_bfloat16*)alloc(8192ULL * 768 * 2);  // 12 MB
    __hip_bfloat16* w1b   = (__hip_bfloat16*)alloc(2048ULL * 768 * 2);  // 3 MB
    __hip_bfloat16* w_rgb = (__hip_bfloat16*)alloc(2048ULL * 1024 * 2); // 4 MB
    __hip_bfloat16* w_outb= (__hip_bfloat16*)alloc(768ULL * 1024 * 2);  // 1.5 MB
    float*          chv   = (float*)alloc(NC * 1024ULL * 4);
    float*          cav   = (float*)alloc(NC * 1024ULL * 4);
    __hip_bfloat16* zb    = bcb;   // overlay

    prep_kernel<<<PREP_BLOCKS, 256, 0, stream>>>(x, w1, w_rg, w_out, conv_w,
                                                 xb, w1b, w_rgb, w_outb, wbigb, bbp);

    // h = x @ w1.T + b1, fused split: ab = bf16(gelu), bbp = bf16 (rows +3)
    {
        dim3 grid(T_LEN / 128, 2048 / 256);
        gemm_mfma<256, 2><<<grid, 512, 0, stream>>>(xb, w1b, b1, ab, DM, DM, 2048, bbp);
    }

    // bc = causal conv (shift-reuse kernel) -> bf16
    {
        dim3 grid(T_LEN / 128, 1024 / 128);
        conv_mfma<<<grid, 256, 0, stream>>>(bbp, wbigb, bcb);
    }

    // g_pre = bc @ w_rg.T + b_rg -> bf16
    {
        dim3 grid(T_LEN / 128, 2048 / 256);
        gemm_mfma<256, 1><<<grid, 512, 0, stream>>>(bcb, w_rgb, b_rg, gpre, DR, DR, 2048, nullptr);
    }

    // chunked scan with fused gates; z = ab*y -> bf16 (overlays bcb)
    {
        dim3 gs(NC, DR / 256);
        scan_pass1<<<gs, 256, 0, stream>>>(gpre, bcb, Lambda, chv, cav);
        scan_combine<<<DR / 256, 256, 0, stream>>>(chv, cav);
        scan_pass2<<<gs, 256, 0, stream>>>(gpre, bcb, Lambda, chv, ab, zb);
    }

    // out = z @ w_out.T + b_out -> fp32
    {
        dim3 grid(T_LEN / 128, DM / 64);
        gemm_mfma<64, 0><<<grid, 256, 0, stream>>>(zb, w_outb, b_out, out, DR, DR, DM, nullptr);
    }
}